// Round 2
// baseline (6900.234 us; speedup 1.0000x reference)
//
#include <hip/hip_runtime.h>

// ---------------------------------------------------------------------------
// Self-attention forward, fp32 baseline (round 1: fix PV call-site arg count).
//   Q = x@WQ, K = x@WK, V = x@WV          (gemm_f32<NN>)
//   Sc = scale * Q_b @ K_b^T              (gemm_f32<NT> fused scale)
//   softmax rows: exp(s - rowmax), store rowsum (no normalize pass)
//   Z_b = (Sc @ V_b) / rowsum             (gemm_f32<NN> fused row-divide)
// All dims are multiples of the 128x128x16 tile.
// ---------------------------------------------------------------------------

#define BM 128
#define BN 128
#define BK 16
#define LDSS 132  // padded LDS row stride (floats); 132%4==0 keeps float4 alignment

template <bool NT, bool SCALE, bool RDIV>
__global__ __launch_bounds__(256, 2) void gemm_f32(
    const float* __restrict__ A,   // M x Kdim row-major
    const float* __restrict__ B,   // NN: Kdim x N ; NT: N x Kdim (row-major)
    float* __restrict__ C,         // M x N row-major
    const float* __restrict__ rdiv,// RDIV: per-row divisor, launch-local rows
    int M, int N, int Kdim, float scale)
{
    __shared__ float As[BK * LDSS];
    __shared__ float Bs[BK * LDSS];

    const int tid = threadIdx.x;
    const int tx = tid & 15;        // 0..15 (n micro)
    const int ty = tid >> 4;        // 0..15 (m micro)
    const int bm = blockIdx.y, bn = blockIdx.x;

    const float* Ab = A + (size_t)bm * BM * Kdim;

    // A-tile (and NT B-tile) load mapping: 128 rows x 16 cols, float4 chunks.
    // Consecutive lanes cover consecutive 16B of the same row -> coalesced.
    const int a_row = tid >> 2;          // 0..63 (second half at +64)
    const int a_col = (tid & 3) * 4;     // 0,4,8,12
    // NN B-tile: 16 rows x 128 cols
    const int b_row = tid >> 5;          // 0..7 (second half at +8)
    const int b_col = (tid & 31) * 4;    // 0..124

    float acc[8][8] = {};

    for (int k0 = 0; k0 < Kdim; k0 += BK) {
        float4 av0 = *(const float4*)(Ab + (size_t)a_row        * Kdim + k0 + a_col);
        float4 av1 = *(const float4*)(Ab + (size_t)(a_row + 64) * Kdim + k0 + a_col);
        float4 bv0, bv1;
        if (NT) {
            const float* Bb = B + (size_t)bn * BN * Kdim;
            bv0 = *(const float4*)(Bb + (size_t)a_row        * Kdim + k0 + a_col);
            bv1 = *(const float4*)(Bb + (size_t)(a_row + 64) * Kdim + k0 + a_col);
        } else {
            const float* Bb = B + (size_t)bn * BN;
            bv0 = *(const float4*)(Bb + (size_t)(k0 + b_row)     * N + b_col);
            bv1 = *(const float4*)(Bb + (size_t)(k0 + b_row + 8) * N + b_col);
        }

        __syncthreads();  // previous iteration's LDS reads done

        {   // scatter A transposed: As[k][m]
            float va[8] = {av0.x, av0.y, av0.z, av0.w, av1.x, av1.y, av1.z, av1.w};
            #pragma unroll
            for (int i = 0; i < 4; ++i) {
                As[(a_col + i) * LDSS + a_row]      = va[i];
                As[(a_col + i) * LDSS + a_row + 64] = va[4 + i];
            }
        }
        if (NT) {
            float vb[8] = {bv0.x, bv0.y, bv0.z, bv0.w, bv1.x, bv1.y, bv1.z, bv1.w};
            #pragma unroll
            for (int i = 0; i < 4; ++i) {
                Bs[(a_col + i) * LDSS + a_row]      = vb[i];
                Bs[(a_col + i) * LDSS + a_row + 64] = vb[4 + i];
            }
        } else {
            *(float4*)&Bs[b_row * LDSS + b_col]       = bv0;
            *(float4*)&Bs[(b_row + 8) * LDSS + b_col] = bv1;
        }
        __syncthreads();

        #pragma unroll
        for (int kk = 0; kk < BK; ++kk) {
            float4 x0 = *(const float4*)&As[kk * LDSS + ty * 4];
            float4 x1 = *(const float4*)&As[kk * LDSS + 64 + ty * 4];
            float4 y0 = *(const float4*)&Bs[kk * LDSS + tx * 4];
            float4 y1 = *(const float4*)&Bs[kk * LDSS + 64 + tx * 4];
            float xa[8] = {x0.x, x0.y, x0.z, x0.w, x1.x, x1.y, x1.z, x1.w};
            float yb[8] = {y0.x, y0.y, y0.z, y0.w, y1.x, y1.y, y1.z, y1.w};
            #pragma unroll
            for (int i = 0; i < 8; ++i)
                #pragma unroll
                for (int j = 0; j < 8; ++j)
                    acc[i][j] += xa[i] * yb[j];
        }
    }

    #pragma unroll
    for (int i = 0; i < 8; ++i) {
        int mrow = bm * BM + ((i < 4) ? (ty * 4 + i) : (64 + ty * 4 + (i - 4)));
        float f = SCALE ? scale : 1.0f;
        if (RDIV) f *= 1.0f / rdiv[mrow];
        float4 c0 = make_float4(acc[i][0] * f, acc[i][1] * f, acc[i][2] * f, acc[i][3] * f);
        float4 c1 = make_float4(acc[i][4] * f, acc[i][5] * f, acc[i][6] * f, acc[i][7] * f);
        float* Crow = C + (size_t)mrow * N + (size_t)bn * BN;
        *(float4*)(Crow + tx * 4)      = c0;
        *(float4*)(Crow + 64 + tx * 4) = c1;
    }
}

// One block per row: s -> exp(s - max); rowsum stored (PV epilogue divides).
__global__ __launch_bounds__(256) void softmax_rows(
    float* __restrict__ Sc, float* __restrict__ rowsum, int ncol)
{
    __shared__ float red[8];
    const int tid = threadIdx.x;
    float* row = Sc + (size_t)blockIdx.x * ncol;

    float m = -1e30f;
    for (int c = tid * 4; c < ncol; c += 1024) {
        float4 v = *(const float4*)(row + c);
        m = fmaxf(m, fmaxf(fmaxf(v.x, v.y), fmaxf(v.z, v.w)));
    }
    #pragma unroll
    for (int off = 32; off; off >>= 1) m = fmaxf(m, __shfl_xor(m, off, 64));
    if ((tid & 63) == 0) red[tid >> 6] = m;
    __syncthreads();
    const float rmax = fmaxf(fmaxf(red[0], red[1]), fmaxf(red[2], red[3]));

    float s = 0.f;
    for (int c = tid * 4; c < ncol; c += 1024) {
        float4 v = *(const float4*)(row + c);
        v.x = __expf(v.x - rmax);
        v.y = __expf(v.y - rmax);
        v.z = __expf(v.z - rmax);
        v.w = __expf(v.w - rmax);
        s += v.x + v.y + v.z + v.w;
        *(float4*)(row + c) = v;
    }
    #pragma unroll
    for (int off = 32; off; off >>= 1) s += __shfl_xor(s, off, 64);
    __syncthreads();
    if ((tid & 63) == 0) red[4 + (tid >> 6)] = s;
    __syncthreads();
    if (tid == 0) rowsum[blockIdx.x] = red[4] + red[5] + red[6] + red[7];
}

extern "C" void kernel_launch(void* const* d_in, const int* in_sizes, int n_in,
                              void* d_out, int out_size, void* d_ws, size_t ws_size,
                              hipStream_t stream) {
    const int Bb = 4, S = 4096, D = 1024;
    const size_t MT = (size_t)Bb * S;  // 16384 tokens

    const float* x  = (const float*)d_in[0];
    const float* WQ = (const float*)d_in[1];
    const float* WK = (const float*)d_in[2];
    const float* WV = (const float*)d_in[3];
    float* out = (float*)d_out;

    float* ws = (float*)d_ws;
    float* Q  = ws;
    float* Km = Q + MT * D;
    float* V  = Km + MT * D;
    float* rowsum = V + MT * D;          // up to S floats used per chunk
    float* Sc = rowsum + 16384;          // R x S score buffer (reused per chunk)

    // Choose Q-row chunk size R by available workspace (needs R*S floats for Sc).
    const size_t base_f = 3 * MT * D + 16384;
    size_t avail_f = (ws_size / 4 > base_f) ? (ws_size / 4 - base_f) : 0;
    int R = S;
    while (R > 128 && (size_t)R * S > avail_f) R >>= 1;

    dim3 blk(256);
    const float scale = 0.03125f;  // 1/sqrt(1024)

    // Projections: [16384,1024] @ [1024,1024]
    dim3 gproj(D / BN, MT / BM);
    gemm_f32<false, false, false><<<gproj, blk, 0, stream>>>(x, WQ, Q,  nullptr, (int)MT, D, D, 1.f);
    gemm_f32<false, false, false><<<gproj, blk, 0, stream>>>(x, WK, Km, nullptr, (int)MT, D, D, 1.f);
    gemm_f32<false, false, false><<<gproj, blk, 0, stream>>>(x, WV, V,  nullptr, (int)MT, D, D, 1.f);

    for (int b = 0; b < Bb; ++b) {
        const float* Kb = Km + (size_t)b * S * D;
        const float* Vb = V  + (size_t)b * S * D;
        for (int r0 = 0; r0 < S; r0 += R) {
            const float* Qb = Q + ((size_t)b * S + r0) * D;
            float* Zb = out + ((size_t)b * S + r0) * D;
            // Sc[R x S] = scale * Qb @ Kb^T
            gemm_f32<true, true, false><<<dim3(S / BN, R / BM), blk, 0, stream>>>(
                Qb, Kb, Sc, nullptr, R, S, D, scale);
            softmax_rows<<<dim3(R), blk, 0, stream>>>(Sc, rowsum, S);
            // Zb[R x D] = (Sc @ Vb) / rowsum
            gemm_f32<false, false, true><<<dim3(D / BN, R / BM), blk, 0, stream>>>(
                Sc, Vb, Zb, rowsum, R, D, S, 1.f);
        }
    }
}

// Round 3
// 1333.121 us; speedup vs baseline: 5.1760x; 5.1760x over previous
//
#include <hip/hip_runtime.h>

// ---------------------------------------------------------------------------
// Self-attention forward via fp16 split-MFMA (round 2).
//   Numerics: x' = 256x, W' = 256W split into fp16 hi/lo (lo in normal range).
//   Q'' = 256Q as fp16 hi/lo (3-term split GEMM), same for K.
//   VT'' = 256*V^T (1-term GEMM, A=WvT', B=xhi').
//   Sc = QK^T/32 fp32 (3-term split GEMM, scale 2^-21).
//   softmax rows -> P fp16 (unnormalized), rowsum fp32.
//   Z = P @ V / rowsum  (1-term GEMM, A=P, B=VT'', scale 2^-8, rdiv=rowsum).
// GEMM kernel: NT (both operands [row][K] packed), 128x128x32 tile, 4 waves,
// global_load_lds 16B staging, mfma_f32_16x16x32_f16.
// ---------------------------------------------------------------------------

typedef _Float16 half8 __attribute__((ext_vector_type(8)));
typedef _Float16 half4v __attribute__((ext_vector_type(4)));
typedef float floatx4 __attribute__((ext_vector_type(4)));

__device__ __forceinline__ void glds16(const _Float16* g, _Float16* l) {
    __builtin_amdgcn_global_load_lds(
        (const __attribute__((address_space(1))) void*)g,
        (__attribute__((address_space(3))) void*)l, 16, 0, 0);
}

// Stage one 128x32 half tile (8 KB) from g (row stride ldg halves) into s.
// 512 16B-chunks; chunk c = i*256+tid -> row c>>2, col8 (c&3)*8.
// LDS dest: wave-uniform base + lane*16 (HW) == chunk order. No padding.
__device__ __forceinline__ void stage_tile(_Float16* s, const _Float16* g,
                                           int ldg, int tid) {
    const int wb = (tid & 192) * 8;  // wave base in halves
    {
        const int c = tid;
        glds16(g + (size_t)(c >> 2) * ldg + (c & 3) * 8, s + wb);
    }
    {
        const int c = 256 + tid;
        glds16(g + (size_t)(c >> 2) * ldg + (c & 3) * 8, s + 2048 + wb);
    }
}

// OMODE: 0 = f32 out (acc*scale), 1 = f32 out (acc*scale/rdiv[row]),
//        2 = half out (acc*scale), 3 = split half out (hi,lo of acc*scale)
template <bool SPLITIN, int OMODE>
__global__ __launch_bounds__(256, 2) void gemm_nt(
    const _Float16* __restrict__ AH, const _Float16* __restrict__ AL,
    const _Float16* BH, const _Float16* BL,
    void* out0, void* out1,
    const float* __restrict__ rdiv, float scale, int M, int N, int K,
    const _Float16* BH2, const _Float16* BL2, void* o0b, void* o1b)
{
    if (blockIdx.z == 1) { BH = BH2; BL = BL2; out0 = o0b; out1 = o1b; }

    __shared__ _Float16 sAH[128 * 32];
    __shared__ _Float16 sBH[128 * 32];
    __shared__ _Float16 sAL[SPLITIN ? 128 * 32 : 8];
    __shared__ _Float16 sBL[SPLITIN ? 128 * 32 : 8];

    const int tid = threadIdx.x;
    const int bm = blockIdx.y, bn = blockIdx.x;
    const int lane = tid & 63, quad = lane >> 4, lrow = lane & 15;
    const int wave = tid >> 6, wm = wave >> 1, wn = wave & 1;

    const _Float16* Ab = AH + (size_t)bm * 128 * K;
    const _Float16* Bb = BH + (size_t)bn * 128 * K;
    const _Float16* AbL = SPLITIN ? (AL + (size_t)bm * 128 * K) : nullptr;
    const _Float16* BbL = SPLITIN ? (BL + (size_t)bn * 128 * K) : nullptr;

    floatx4 acc[4][4] = {};

    const int aoff = (wm * 64 + lrow) * 32 + quad * 8;
    const int boff = (wn * 64 + lrow) * 32 + quad * 8;

    for (int k0 = 0; k0 < K; k0 += 32) {
        stage_tile(sAH, Ab + k0, K, tid);
        stage_tile(sBH, Bb + k0, K, tid);
        if (SPLITIN) {
            stage_tile(sAL, AbL + k0, K, tid);
            stage_tile(sBL, BbL + k0, K, tid);
        }
        __syncthreads();  // drains vmcnt -> LDS tiles valid

        half8 aH[4], bH[4], aL[4], bL[4];
        #pragma unroll
        for (int i = 0; i < 4; ++i) {
            aH[i] = *(const half8*)&sAH[aoff + i * 16 * 32];
            bH[i] = *(const half8*)&sBH[boff + i * 16 * 32];
            if (SPLITIN) {
                aL[i] = *(const half8*)&sAL[aoff + i * 16 * 32];
                bL[i] = *(const half8*)&sBL[boff + i * 16 * 32];
            }
        }
        #pragma unroll
        for (int mi = 0; mi < 4; ++mi)
            #pragma unroll
            for (int nj = 0; nj < 4; ++nj) {
                acc[mi][nj] = __builtin_amdgcn_mfma_f32_16x16x32_f16(
                    aH[mi], bH[nj], acc[mi][nj], 0, 0, 0);
                if (SPLITIN) {
                    acc[mi][nj] = __builtin_amdgcn_mfma_f32_16x16x32_f16(
                        aH[mi], bL[nj], acc[mi][nj], 0, 0, 0);
                    acc[mi][nj] = __builtin_amdgcn_mfma_f32_16x16x32_f16(
                        aL[mi], bH[nj], acc[mi][nj], 0, 0, 0);
                }
            }
        __syncthreads();  // all waves done reading before next stage
    }

    // Epilogue. C/D layout: row = quad*4+reg, col = lane&15 (m89-verified).
    #pragma unroll
    for (int mi = 0; mi < 4; ++mi) {
        #pragma unroll
        for (int r = 0; r < 4; ++r) {
            const int grow = bm * 128 + wm * 64 + mi * 16 + quad * 4 + r;
            float s = scale;
            if (OMODE == 1) s = scale / rdiv[grow];
            #pragma unroll
            for (int nj = 0; nj < 4; ++nj) {
                const int gcol = bn * 128 + wn * 64 + nj * 16 + lrow;
                const float v = acc[mi][nj][r] * s;
                const size_t idx = (size_t)grow * N + gcol;
                if (OMODE <= 1) {
                    ((float*)out0)[idx] = v;
                } else if (OMODE == 2) {
                    ((_Float16*)out0)[idx] = (_Float16)v;
                } else {
                    const _Float16 h = (_Float16)v;
                    ((_Float16*)out0)[idx] = h;
                    ((_Float16*)out1)[idx] = (_Float16)(v - (float)h);
                }
            }
        }
    }
}

// x -> 256x split into fp16 hi/lo.
__global__ __launch_bounds__(256) void split_scale(
    const float* __restrict__ x, _Float16* __restrict__ hi,
    _Float16* __restrict__ lo, int n)
{
    int i = (blockIdx.x * 256 + threadIdx.x) * 4;
    const int stride = gridDim.x * 256 * 4;
    for (; i < n; i += stride) {
        float4 v = *(const float4*)(x + i);
        float a[4] = {v.x * 256.f, v.y * 256.f, v.z * 256.f, v.w * 256.f};
        half4v h, l;
        #pragma unroll
        for (int j = 0; j < 4; ++j) {
            h[j] = (_Float16)a[j];
            l[j] = (_Float16)(a[j] - (float)h[j]);
        }
        *(half4v*)(hi + i) = h;
        *(half4v*)(lo + i) = l;
    }
}

// W [dim][dim] fp32 -> 256*W^T split fp16 hi/lo (loT may be null).
__global__ __launch_bounds__(256) void wprep(
    const float* __restrict__ W, _Float16* __restrict__ hiT,
    _Float16* __restrict__ loT, int dim)
{
    __shared__ float t[32][33];
    const int n0 = blockIdx.x * 32, k0 = blockIdx.y * 32;
    const int tx = threadIdx.x, ty = threadIdx.y;  // block (32,8)
    #pragma unroll
    for (int i = 0; i < 4; ++i)
        t[ty + 8 * i][tx] = 256.f * W[(size_t)(k0 + ty + 8 * i) * dim + n0 + tx];
    __syncthreads();
    #pragma unroll
    for (int i = 0; i < 4; ++i) {
        const int nn = ty + 8 * i;
        const float v = t[tx][nn];  // 256*W[k0+tx][n0+nn]
        const _Float16 h = (_Float16)v;
        const size_t o = (size_t)(n0 + nn) * dim + k0 + tx;
        hiT[o] = h;
        if (loT) loT[o] = (_Float16)(v - (float)h);
    }
}

// One block per row of Sc[4096]: P = exp(s - rowmax) fp16, rowsum fp32.
__global__ __launch_bounds__(256) void softmax_p(
    const float* __restrict__ Sc, _Float16* __restrict__ P,
    float* __restrict__ rowsum)
{
    __shared__ float red[8];
    const int tid = threadIdx.x;
    const float* row = Sc + (size_t)blockIdx.x * 4096;
    _Float16* prow = P + (size_t)blockIdx.x * 4096;

    float m = -1e30f;
    for (int c = tid * 4; c < 4096; c += 1024) {
        float4 v = *(const float4*)(row + c);
        m = fmaxf(m, fmaxf(fmaxf(v.x, v.y), fmaxf(v.z, v.w)));
    }
    #pragma unroll
    for (int off = 32; off; off >>= 1) m = fmaxf(m, __shfl_xor(m, off, 64));
    if ((tid & 63) == 0) red[tid >> 6] = m;
    __syncthreads();
    const float rmax = fmaxf(fmaxf(red[0], red[1]), fmaxf(red[2], red[3]));

    float s = 0.f;
    for (int c = tid * 4; c < 4096; c += 1024) {
        float4 v = *(const float4*)(row + c);
        float p0 = __expf(v.x - rmax), p1 = __expf(v.y - rmax);
        float p2 = __expf(v.z - rmax), p3 = __expf(v.w - rmax);
        s += p0 + p1 + p2 + p3;
        half4v h = {(_Float16)p0, (_Float16)p1, (_Float16)p2, (_Float16)p3};
        *(half4v*)(prow + c) = h;
    }
    #pragma unroll
    for (int off = 32; off; off >>= 1) s += __shfl_xor(s, off, 64);
    __syncthreads();
    if ((tid & 63) == 0) red[4 + (tid >> 6)] = s;
    __syncthreads();
    if (tid == 0) rowsum[blockIdx.x] = red[4] + red[5] + red[6] + red[7];
}

extern "C" void kernel_launch(void* const* d_in, const int* in_sizes, int n_in,
                              void* d_out, int out_size, void* d_ws, size_t ws_size,
                              hipStream_t stream) {
    const int Bb = 4, S = 4096, D = 1024;
    const size_t SD = (size_t)S * D;      // 4.19M
    const size_t SS = (size_t)S * S;      // 16.8M

    const float* x  = (const float*)d_in[0];
    const float* WQ = (const float*)d_in[1];
    const float* WK = (const float*)d_in[2];
    const float* WV = (const float*)d_in[3];
    float* out = (float*)d_out;

    // Workspace layout (162 MB total; ws_size inferred >= ~210 MB from R0).
    char* w = (char*)d_ws;
    _Float16* WQhT = (_Float16*)w;  w += (size_t)D * D * 2;
    _Float16* WQlT = (_Float16*)w;  w += (size_t)D * D * 2;
    _Float16* WKhT = (_Float16*)w;  w += (size_t)D * D * 2;
    _Float16* WKlT = (_Float16*)w;  w += (size_t)D * D * 2;
    _Float16* WvhT = (_Float16*)w;  w += (size_t)D * D * 2;
    _Float16* xhi  = (_Float16*)w;  w += SD * 2;
    _Float16* xlo  = (_Float16*)w;  w += SD * 2;
    _Float16* Qhi  = (_Float16*)w;  w += SD * 2;
    _Float16* Qlo  = (_Float16*)w;  w += SD * 2;
    _Float16* Khi  = (_Float16*)w;  w += SD * 2;
    _Float16* Klo  = (_Float16*)w;  w += SD * 2;
    _Float16* VT   = (_Float16*)w;  w += SD * 2;
    float*    rowsum = (float*)w;   w += (size_t)S * 4;
    float*    Sc   = (float*)w;     w += SS * 4;
    _Float16* P    = (_Float16*)w;  w += SS * 2;

    const float kInv256 = 0.00390625f;           // 2^-8
    const float kScScale = 4.76837158203125e-7f; // 2^-21 = 1/(65536*32)

    dim3 blk(256);

    // Weight prep: 256*W^T split fp16 (Wv: hi only).
    wprep<<<dim3(32, 32), dim3(32, 8), 0, stream>>>(WQ, WQhT, WQlT, D);
    wprep<<<dim3(32, 32), dim3(32, 8), 0, stream>>>(WK, WKhT, WKlT, D);
    wprep<<<dim3(32, 32), dim3(32, 8), 0, stream>>>(WV, WvhT, nullptr, D);

    for (int b = 0; b < Bb; ++b) {
        const float* xb = x + (size_t)b * SD;
        float* outb = out + (size_t)b * SD;

        split_scale<<<dim3(4096), blk, 0, stream>>>(xb, xhi, xlo, (int)SD);

        // Q and K projections (z-fused): [4096x1024] = split(x') @ split(W'^T)
        gemm_nt<true, 3><<<dim3(D / 128, S / 128, 2), blk, 0, stream>>>(
            xhi, xlo, WQhT, WQlT, Qhi, Qlo, nullptr, kInv256, S, D, D,
            WKhT, WKlT, Khi, Klo);

        // VT'' = 256*V^T: [1024x4096] = WvhT' @ xhi'^T
        gemm_nt<false, 2><<<dim3(S / 128, D / 128, 1), blk, 0, stream>>>(
            WvhT, nullptr, xhi, nullptr, VT, nullptr, nullptr, kInv256,
            D, S, D, nullptr, nullptr, nullptr, nullptr);

        // Sc = QK^T/32 fp32: [4096x4096]
        gemm_nt<true, 0><<<dim3(S / 128, S / 128, 1), blk, 0, stream>>>(
            Qhi, Qlo, Khi, Klo, Sc, nullptr, nullptr, kScScale, S, S, D,
            nullptr, nullptr, nullptr, nullptr);

        softmax_p<<<dim3(S), blk, 0, stream>>>(Sc, P, rowsum);

        // Z = (P @ V) / rowsum: [4096x1024], acc = 256*PV -> *2^-8/rowsum
        gemm_nt<false, 1><<<dim3(D / 128, S / 128, 1), blk, 0, stream>>>(
            P, nullptr, VT, nullptr, outb, nullptr, rowsum, kInv256, S, D, S,
            nullptr, nullptr, nullptr, nullptr);
    }
}

// Round 4
// 1311.838 us; speedup vs baseline: 5.2600x; 1.0162x over previous
//
#include <hip/hip_runtime.h>

// ---------------------------------------------------------------------------
// Self-attention forward via fp16 split-MFMA (round 3).
//   R2 + (a) score epilogue emits per-(row, nblock, wave) partial rowmax ->
//   softmax becomes single-pass (saves one full 64MB Sc read per batch);
//   (b) staging addresses hoisted out of K-loop (pointer += 32 halves);
//   (c) wprep merged into one z=3 launch.
// GEMM kernel unchanged structurally: NT, 128x128x32 tile, 4 waves,
// global_load_lds 16B staging, mfma_f32_16x16x32_f16 (m97-plateau ~860 TF).
// ---------------------------------------------------------------------------

typedef _Float16 half8 __attribute__((ext_vector_type(8)));
typedef _Float16 half4v __attribute__((ext_vector_type(4)));
typedef float floatx4 __attribute__((ext_vector_type(4)));

__device__ __forceinline__ void glds16(const _Float16* g, _Float16* l) {
    __builtin_amdgcn_global_load_lds(
        (const __attribute__((address_space(1))) void*)g,
        (__attribute__((address_space(3))) void*)l, 16, 0, 0);
}

// OMODE: 0 = f32 out (acc*scale), 1 = f32 out (acc*scale/rdiv[row]),
//        2 = half out (acc*scale), 3 = split half out (hi,lo of acc*scale)
// PMAX: epilogue writes per-(row, n-block, wave-n) max to pmax[row*64+bn*2+wn]
template <bool SPLITIN, int OMODE, bool PMAX>
__global__ __launch_bounds__(256, 2) void gemm_nt(
    const _Float16* __restrict__ AH, const _Float16* __restrict__ AL,
    const _Float16* BH, const _Float16* BL,
    void* out0, void* out1,
    const float* __restrict__ rdiv, float* __restrict__ pmax,
    float scale, int M, int N, int K,
    const _Float16* BH2, const _Float16* BL2, void* o0b, void* o1b)
{
    if (blockIdx.z == 1) { BH = BH2; BL = BL2; out0 = o0b; out1 = o1b; }

    __shared__ _Float16 sAH[128 * 32];
    __shared__ _Float16 sBH[128 * 32];
    __shared__ _Float16 sAL[SPLITIN ? 128 * 32 : 8];
    __shared__ _Float16 sBL[SPLITIN ? 128 * 32 : 8];

    const int tid = threadIdx.x;
    const int bm = blockIdx.y, bn = blockIdx.x;
    const int lane = tid & 63, quad = lane >> 4, lrow = lane & 15;
    const int wave = tid >> 6, wm = wave >> 1, wn = wave & 1;

    // Hoisted staging pointers: chunk c = {tid, 256+tid} -> row c>>2, col16B c&3.
    const int wb = (tid & 192) * 8;  // LDS wave base (halves)
    const size_t g0 = (size_t)(tid >> 2) * K + (tid & 3) * 8;
    const size_t g1 = (size_t)((256 + tid) >> 2) * K + (tid & 3) * 8;
    const _Float16* pA0 = AH + (size_t)bm * 128 * K + g0;
    const _Float16* pA1 = AH + (size_t)bm * 128 * K + g1;
    const _Float16* pB0 = BH + (size_t)bn * 128 * K + g0;
    const _Float16* pB1 = BH + (size_t)bn * 128 * K + g1;
    const _Float16* pA0L = SPLITIN ? (AL + (size_t)bm * 128 * K + g0) : nullptr;
    const _Float16* pA1L = SPLITIN ? (AL + (size_t)bm * 128 * K + g1) : nullptr;
    const _Float16* pB0L = SPLITIN ? (BL + (size_t)bn * 128 * K + g0) : nullptr;
    const _Float16* pB1L = SPLITIN ? (BL + (size_t)bn * 128 * K + g1) : nullptr;

    floatx4 acc[4][4] = {};

    const int aoff = (wm * 64 + lrow) * 32 + quad * 8;
    const int boff = (wn * 64 + lrow) * 32 + quad * 8;

    for (int k0 = 0; k0 < K; k0 += 32) {
        glds16(pA0, sAH + wb);        glds16(pA1, sAH + 2048 + wb);
        glds16(pB0, sBH + wb);        glds16(pB1, sBH + 2048 + wb);
        if (SPLITIN) {
            glds16(pA0L, sAL + wb);   glds16(pA1L, sAL + 2048 + wb);
            glds16(pB0L, sBL + wb);   glds16(pB1L, sBL + 2048 + wb);
        }
        pA0 += 32; pA1 += 32; pB0 += 32; pB1 += 32;
        if (SPLITIN) { pA0L += 32; pA1L += 32; pB0L += 32; pB1L += 32; }
        __syncthreads();  // drains vmcnt -> LDS tiles valid

        half8 aH[4], bH[4], aL[4], bL[4];
        #pragma unroll
        for (int i = 0; i < 4; ++i) {
            aH[i] = *(const half8*)&sAH[aoff + i * 16 * 32];
            bH[i] = *(const half8*)&sBH[boff + i * 16 * 32];
            if (SPLITIN) {
                aL[i] = *(const half8*)&sAL[aoff + i * 16 * 32];
                bL[i] = *(const half8*)&sBL[boff + i * 16 * 32];
            }
        }
        #pragma unroll
        for (int mi = 0; mi < 4; ++mi)
            #pragma unroll
            for (int nj = 0; nj < 4; ++nj) {
                acc[mi][nj] = __builtin_amdgcn_mfma_f32_16x16x32_f16(
                    aH[mi], bH[nj], acc[mi][nj], 0, 0, 0);
                if (SPLITIN) {
                    acc[mi][nj] = __builtin_amdgcn_mfma_f32_16x16x32_f16(
                        aH[mi], bL[nj], acc[mi][nj], 0, 0, 0);
                    acc[mi][nj] = __builtin_amdgcn_mfma_f32_16x16x32_f16(
                        aL[mi], bH[nj], acc[mi][nj], 0, 0, 0);
                }
            }
        __syncthreads();  // all waves done reading before next stage
    }

    // Epilogue. C/D layout: row = quad*4+reg, col = lane&15 (m89-verified).
    #pragma unroll
    for (int mi = 0; mi < 4; ++mi) {
        #pragma unroll
        for (int r = 0; r < 4; ++r) {
            const int grow = bm * 128 + wm * 64 + mi * 16 + quad * 4 + r;
            float s = scale;
            if (OMODE == 1) s = scale / rdiv[grow];
            float v[4];
            #pragma unroll
            for (int nj = 0; nj < 4; ++nj) v[nj] = acc[mi][nj][r] * s;
            if (PMAX) {
                float mx = fmaxf(fmaxf(v[0], v[1]), fmaxf(v[2], v[3]));
                #pragma unroll
                for (int off = 1; off < 16; off <<= 1)
                    mx = fmaxf(mx, __shfl_xor(mx, off));
                if (lrow == 0) pmax[(size_t)grow * 64 + bn * 2 + wn] = mx;
            }
            #pragma unroll
            for (int nj = 0; nj < 4; ++nj) {
                const int gcol = bn * 128 + wn * 64 + nj * 16 + lrow;
                const size_t idx = (size_t)grow * N + gcol;
                if (OMODE <= 1) {
                    ((float*)out0)[idx] = v[nj];
                } else if (OMODE == 2) {
                    ((_Float16*)out0)[idx] = (_Float16)v[nj];
                } else {
                    const _Float16 h = (_Float16)v[nj];
                    ((_Float16*)out0)[idx] = h;
                    ((_Float16*)out1)[idx] = (_Float16)(v[nj] - (float)h);
                }
            }
        }
    }
}

// x -> 256x split into fp16 hi/lo.
__global__ __launch_bounds__(256) void split_scale(
    const float* __restrict__ x, _Float16* __restrict__ hi,
    _Float16* __restrict__ lo, int n)
{
    int i = (blockIdx.x * 256 + threadIdx.x) * 4;
    const int stride = gridDim.x * 256 * 4;
    for (; i < n; i += stride) {
        float4 v = *(const float4*)(x + i);
        float a[4] = {v.x * 256.f, v.y * 256.f, v.z * 256.f, v.w * 256.f};
        half4v h, l;
        #pragma unroll
        for (int j = 0; j < 4; ++j) {
            h[j] = (_Float16)a[j];
            l[j] = (_Float16)(a[j] - (float)h[j]);
        }
        *(half4v*)(hi + i) = h;
        *(half4v*)(lo + i) = l;
    }
}

// W [dim][dim] fp32 -> 256*W^T split fp16 hi/lo; z picks {WQ, WK, WV}.
__global__ __launch_bounds__(256) void wprep3(
    const float* __restrict__ W0, const float* __restrict__ W1,
    const float* __restrict__ W2,
    _Float16* __restrict__ h0, _Float16* __restrict__ l0,
    _Float16* __restrict__ h1, _Float16* __restrict__ l1,
    _Float16* __restrict__ h2, int dim)
{
    const int z = blockIdx.z;
    const float* W = (z == 0) ? W0 : (z == 1) ? W1 : W2;
    _Float16* hiT = (z == 0) ? h0 : (z == 1) ? h1 : h2;
    _Float16* loT = (z == 0) ? l0 : (z == 1) ? l1 : nullptr;

    __shared__ float t[32][33];
    const int n0 = blockIdx.x * 32, k0 = blockIdx.y * 32;
    const int tx = threadIdx.x, ty = threadIdx.y;  // block (32,8)
    #pragma unroll
    for (int i = 0; i < 4; ++i)
        t[ty + 8 * i][tx] = 256.f * W[(size_t)(k0 + ty + 8 * i) * dim + n0 + tx];
    __syncthreads();
    #pragma unroll
    for (int i = 0; i < 4; ++i) {
        const int nn = ty + 8 * i;
        const float v = t[tx][nn];  // 256*W[k0+tx][n0+nn]
        const _Float16 h = (_Float16)v;
        const size_t o = (size_t)(n0 + nn) * dim + k0 + tx;
        hiT[o] = h;
        if (loT) loT[o] = (_Float16)(v - (float)h);
    }
}

// One block per row: single pass. rowmax from pmax partials (64/row);
// P = exp(s - rowmax) fp16 (unnormalized), rowsum fp32.
__global__ __launch_bounds__(256) void softmax_p(
    const float* __restrict__ Sc, const float* __restrict__ pmax,
    _Float16* __restrict__ P, float* __restrict__ rowsum)
{
    __shared__ float red[8];
    const int tid = threadIdx.x;
    const int row = blockIdx.x;
    const float* srow = Sc + (size_t)row * 4096;
    _Float16* prow = P + (size_t)row * 4096;

    if (tid < 64) {
        float m = pmax[(size_t)row * 64 + tid];
        #pragma unroll
        for (int off = 32; off; off >>= 1) m = fmaxf(m, __shfl_xor(m, off));
        if (tid == 0) red[0] = m;
    }
    __syncthreads();
    const float rmax = red[0];

    float s = 0.f;
    for (int c = tid * 4; c < 4096; c += 1024) {
        float4 v = *(const float4*)(srow + c);
        float p0 = __expf(v.x - rmax), p1 = __expf(v.y - rmax);
        float p2 = __expf(v.z - rmax), p3 = __expf(v.w - rmax);
        s += p0 + p1 + p2 + p3;
        half4v h = {(_Float16)p0, (_Float16)p1, (_Float16)p2, (_Float16)p3};
        *(half4v*)(prow + c) = h;
    }
    #pragma unroll
    for (int off = 32; off; off >>= 1) s += __shfl_xor(s, off, 64);
    if ((tid & 63) == 0) red[4 + (tid >> 6)] = s;
    __syncthreads();
    if (tid == 0) rowsum[row] = red[4] + red[5] + red[6] + red[7];
}

extern "C" void kernel_launch(void* const* d_in, const int* in_sizes, int n_in,
                              void* d_out, int out_size, void* d_ws, size_t ws_size,
                              hipStream_t stream) {
    const int Bb = 4, S = 4096, D = 1024;
    const size_t SD = (size_t)S * D;      // 4.19M
    const size_t SS = (size_t)S * S;      // 16.8M

    const float* x  = (const float*)d_in[0];
    const float* WQ = (const float*)d_in[1];
    const float* WK = (const float*)d_in[2];
    const float* WV = (const float*)d_in[3];
    float* out = (float*)d_out;

    // Workspace layout (~163 MB; ws_size in [209.7, 218) MB per R0 probe).
    char* w = (char*)d_ws;
    _Float16* WQhT = (_Float16*)w;  w += (size_t)D * D * 2;
    _Float16* WQlT = (_Float16*)w;  w += (size_t)D * D * 2;
    _Float16* WKhT = (_Float16*)w;  w += (size_t)D * D * 2;
    _Float16* WKlT = (_Float16*)w;  w += (size_t)D * D * 2;
    _Float16* WvhT = (_Float16*)w;  w += (size_t)D * D * 2;
    _Float16* xhi  = (_Float16*)w;  w += SD * 2;
    _Float16* xlo  = (_Float16*)w;  w += SD * 2;
    _Float16* Qhi  = (_Float16*)w;  w += SD * 2;
    _Float16* Qlo  = (_Float16*)w;  w += SD * 2;
    _Float16* Khi  = (_Float16*)w;  w += SD * 2;
    _Float16* Klo  = (_Float16*)w;  w += SD * 2;
    _Float16* VT   = (_Float16*)w;  w += SD * 2;
    float*    rowsum = (float*)w;   w += (size_t)S * 4;
    float*    pmax = (float*)w;     w += (size_t)S * 64 * 4;
    float*    Sc   = (float*)w;     w += SS * 4;
    _Float16* P    = (_Float16*)w;  w += SS * 2;

    const float kInv256 = 0.00390625f;           // 2^-8
    const float kScScale = 4.76837158203125e-7f; // 2^-21 = 1/(65536*32)

    dim3 blk(256);

    // Weight prep: 256*W^T split fp16 (Wv: hi only), one z=3 launch.
    wprep3<<<dim3(32, 32, 3), dim3(32, 8), 0, stream>>>(
        WQ, WK, WV, WQhT, WQlT, WKhT, WKlT, WvhT, D);

    for (int b = 0; b < Bb; ++b) {
        const float* xb = x + (size_t)b * SD;
        float* outb = out + (size_t)b * SD;

        split_scale<<<dim3(4096), blk, 0, stream>>>(xb, xhi, xlo, (int)SD);

        // Q and K projections (z-fused): [4096x1024] = split(x') @ split(W'^T)
        gemm_nt<true, 3, false><<<dim3(D / 128, S / 128, 2), blk, 0, stream>>>(
            xhi, xlo, WQhT, WQlT, Qhi, Qlo, nullptr, nullptr, kInv256, S, D, D,
            WKhT, WKlT, Khi, Klo);

        // VT'' = 256*V^T: [1024x4096] = WvhT' @ xhi'^T
        gemm_nt<false, 2, false><<<dim3(S / 128, D / 128, 1), blk, 0, stream>>>(
            WvhT, nullptr, xhi, nullptr, VT, nullptr, nullptr, nullptr, kInv256,
            D, S, D, nullptr, nullptr, nullptr, nullptr);

        // Sc = QK^T/32 fp32 + partial rowmax: [4096x4096]
        gemm_nt<true, 0, true><<<dim3(S / 128, S / 128, 1), blk, 0, stream>>>(
            Qhi, Qlo, Khi, Klo, Sc, nullptr, nullptr, pmax, kScScale, S, S, D,
            nullptr, nullptr, nullptr, nullptr);

        softmax_p<<<dim3(S), blk, 0, stream>>>(Sc, pmax, P, rowsum);

        // Z = (P @ V) / rowsum: [4096x1024], acc = 256*PV -> *2^-8/rowsum
        gemm_nt<false, 1, false><<<dim3(D / 128, S / 128, 1), blk, 0, stream>>>(
            P, nullptr, VT, nullptr, outb, nullptr, rowsum, nullptr, kInv256,
            S, D, S, nullptr, nullptr, nullptr, nullptr);
    }
}

// Round 5
// 1274.859 us; speedup vs baseline: 5.4125x; 1.0290x over previous
//
#include <hip/hip_runtime.h>

// ---------------------------------------------------------------------------
// Self-attention forward via fp16 split-MFMA (round 4).
//   R3 + double-buffered LDS staging in gemm_nt: prologue-stage buf0, then
//   per K-step: ONE barrier -> issue glds(k+1 -> other buf) -> MFMA on cur.
//   Barrier both drains the prefetch (issued ~420 cyc earlier, under the
//   48-MFMA + 16-ds_read compute window) and protects buffer reuse.
//   LDS: split kernels 64 KB (2 blocks/CU), non-split 32 KB.
// ---------------------------------------------------------------------------

typedef _Float16 half8 __attribute__((ext_vector_type(8)));
typedef _Float16 half4v __attribute__((ext_vector_type(4)));
typedef float floatx4 __attribute__((ext_vector_type(4)));

__device__ __forceinline__ void glds16(const _Float16* g, _Float16* l) {
    __builtin_amdgcn_global_load_lds(
        (const __attribute__((address_space(1))) void*)g,
        (__attribute__((address_space(3))) void*)l, 16, 0, 0);
}

// OMODE: 0 = f32 out (acc*scale), 1 = f32 out (acc*scale/rdiv[row]),
//        2 = half out (acc*scale), 3 = split half out (hi,lo of acc*scale)
// PMAX: epilogue writes per-(row, n-block, wave-n) max to pmax[row*64+bn*2+wn]
template <bool SPLITIN, int OMODE, bool PMAX>
__global__ __launch_bounds__(256, 2) void gemm_nt(
    const _Float16* __restrict__ AH, const _Float16* __restrict__ AL,
    const _Float16* BH, const _Float16* BL,
    void* out0, void* out1,
    const float* __restrict__ rdiv, float* __restrict__ pmax,
    float scale, int M, int N, int K,
    const _Float16* BH2, const _Float16* BL2, void* o0b, void* o1b)
{
    if (blockIdx.z == 1) { BH = BH2; BL = BL2; out0 = o0b; out1 = o1b; }

    // Double-buffered tiles: [2][128*32] halves (8 KB per tile buffer).
    __shared__ _Float16 sAH[2 * 128 * 32];
    __shared__ _Float16 sBH[2 * 128 * 32];
    __shared__ _Float16 sAL[SPLITIN ? 2 * 128 * 32 : 8];
    __shared__ _Float16 sBL[SPLITIN ? 2 * 128 * 32 : 8];

    const int tid = threadIdx.x;
    const int bm = blockIdx.y, bn = blockIdx.x;
    const int lane = tid & 63, quad = lane >> 4, lrow = lane & 15;
    const int wave = tid >> 6, wm = wave >> 1, wn = wave & 1;

    // Hoisted staging pointers: chunk c = {tid, 256+tid} -> row c>>2, col16B c&3.
    const int wb = (tid & 192) * 8;  // LDS wave base (halves)
    const size_t g0 = (size_t)(tid >> 2) * K + (tid & 3) * 8;
    const size_t g1 = (size_t)((256 + tid) >> 2) * K + (tid & 3) * 8;
    const _Float16* pA0 = AH + (size_t)bm * 128 * K + g0;
    const _Float16* pA1 = AH + (size_t)bm * 128 * K + g1;
    const _Float16* pB0 = BH + (size_t)bn * 128 * K + g0;
    const _Float16* pB1 = BH + (size_t)bn * 128 * K + g1;
    const _Float16* pA0L = SPLITIN ? (AL + (size_t)bm * 128 * K + g0) : nullptr;
    const _Float16* pA1L = SPLITIN ? (AL + (size_t)bm * 128 * K + g1) : nullptr;
    const _Float16* pB0L = SPLITIN ? (BL + (size_t)bn * 128 * K + g0) : nullptr;
    const _Float16* pB1L = SPLITIN ? (BL + (size_t)bn * 128 * K + g1) : nullptr;

    floatx4 acc[4][4] = {};

    const int aoff = (wm * 64 + lrow) * 32 + quad * 8;
    const int boff = (wn * 64 + lrow) * 32 + quad * 8;

    // Prologue: stage k=0 into buffer 0.
    glds16(pA0, sAH + wb);        glds16(pA1, sAH + 2048 + wb);
    glds16(pB0, sBH + wb);        glds16(pB1, sBH + 2048 + wb);
    if (SPLITIN) {
        glds16(pA0L, sAL + wb);   glds16(pA1L, sAL + 2048 + wb);
        glds16(pB0L, sBL + wb);   glds16(pB1L, sBL + 2048 + wb);
    }
    pA0 += 32; pA1 += 32; pB0 += 32; pB1 += 32;
    if (SPLITIN) { pA0L += 32; pA1L += 32; pB0L += 32; pB1L += 32; }

    int cur = 0;
    for (int k0 = 0; k0 < K; k0 += 32) {
        __syncthreads();  // drains vmcnt: buf[cur] valid; buf[cur^1] free

        if (k0 + 32 < K) {  // prefetch k+1 into the other buffer (async)
            const int nb = (cur ^ 1) * 4096;
            glds16(pA0, sAH + nb + wb);        glds16(pA1, sAH + nb + 2048 + wb);
            glds16(pB0, sBH + nb + wb);        glds16(pB1, sBH + nb + 2048 + wb);
            if (SPLITIN) {
                glds16(pA0L, sAL + nb + wb);   glds16(pA1L, sAL + nb + 2048 + wb);
                glds16(pB0L, sBL + nb + wb);   glds16(pB1L, sBL + nb + 2048 + wb);
            }
            pA0 += 32; pA1 += 32; pB0 += 32; pB1 += 32;
            if (SPLITIN) { pA0L += 32; pA1L += 32; pB0L += 32; pB1L += 32; }
        }

        const int cb = cur * 4096;
        half8 aH[4], bH[4], aL[4], bL[4];
        #pragma unroll
        for (int i = 0; i < 4; ++i) {
            aH[i] = *(const half8*)&sAH[cb + aoff + i * 16 * 32];
            bH[i] = *(const half8*)&sBH[cb + boff + i * 16 * 32];
            if (SPLITIN) {
                aL[i] = *(const half8*)&sAL[cb + aoff + i * 16 * 32];
                bL[i] = *(const half8*)&sBL[cb + boff + i * 16 * 32];
            }
        }
        #pragma unroll
        for (int mi = 0; mi < 4; ++mi)
            #pragma unroll
            for (int nj = 0; nj < 4; ++nj) {
                acc[mi][nj] = __builtin_amdgcn_mfma_f32_16x16x32_f16(
                    aH[mi], bH[nj], acc[mi][nj], 0, 0, 0);
                if (SPLITIN) {
                    acc[mi][nj] = __builtin_amdgcn_mfma_f32_16x16x32_f16(
                        aH[mi], bL[nj], acc[mi][nj], 0, 0, 0);
                    acc[mi][nj] = __builtin_amdgcn_mfma_f32_16x16x32_f16(
                        aL[mi], bH[nj], acc[mi][nj], 0, 0, 0);
                }
            }
        cur ^= 1;
    }

    // Epilogue. C/D layout: row = quad*4+reg, col = lane&15 (m89-verified).
    #pragma unroll
    for (int mi = 0; mi < 4; ++mi) {
        #pragma unroll
        for (int r = 0; r < 4; ++r) {
            const int grow = bm * 128 + wm * 64 + mi * 16 + quad * 4 + r;
            float s = scale;
            if (OMODE == 1) s = scale / rdiv[grow];
            float v[4];
            #pragma unroll
            for (int nj = 0; nj < 4; ++nj) v[nj] = acc[mi][nj][r] * s;
            if (PMAX) {
                float mx = fmaxf(fmaxf(v[0], v[1]), fmaxf(v[2], v[3]));
                #pragma unroll
                for (int off = 1; off < 16; off <<= 1)
                    mx = fmaxf(mx, __shfl_xor(mx, off));
                if (lrow == 0) pmax[(size_t)grow * 64 + bn * 2 + wn] = mx;
            }
            #pragma unroll
            for (int nj = 0; nj < 4; ++nj) {
                const int gcol = bn * 128 + wn * 64 + nj * 16 + lrow;
                const size_t idx = (size_t)grow * N + gcol;
                if (OMODE <= 1) {
                    ((float*)out0)[idx] = v[nj];
                } else if (OMODE == 2) {
                    ((_Float16*)out0)[idx] = (_Float16)v[nj];
                } else {
                    const _Float16 h = (_Float16)v[nj];
                    ((_Float16*)out0)[idx] = h;
                    ((_Float16*)out1)[idx] = (_Float16)(v[nj] - (float)h);
                }
            }
        }
    }
}

// x -> 256x split into fp16 hi/lo.
__global__ __launch_bounds__(256) void split_scale(
    const float* __restrict__ x, _Float16* __restrict__ hi,
    _Float16* __restrict__ lo, int n)
{
    int i = (blockIdx.x * 256 + threadIdx.x) * 4;
    const int stride = gridDim.x * 256 * 4;
    for (; i < n; i += stride) {
        float4 v = *(const float4*)(x + i);
        float a[4] = {v.x * 256.f, v.y * 256.f, v.z * 256.f, v.w * 256.f};
        half4v h, l;
        #pragma unroll
        for (int j = 0; j < 4; ++j) {
            h[j] = (_Float16)a[j];
            l[j] = (_Float16)(a[j] - (float)h[j]);
        }
        *(half4v*)(hi + i) = h;
        *(half4v*)(lo + i) = l;
    }
}

// W [dim][dim] fp32 -> 256*W^T split fp16 hi/lo; z picks {WQ, WK, WV}.
__global__ __launch_bounds__(256) void wprep3(
    const float* __restrict__ W0, const float* __restrict__ W1,
    const float* __restrict__ W2,
    _Float16* __restrict__ h0, _Float16* __restrict__ l0,
    _Float16* __restrict__ h1, _Float16* __restrict__ l1,
    _Float16* __restrict__ h2, int dim)
{
    const int z = blockIdx.z;
    const float* W = (z == 0) ? W0 : (z == 1) ? W1 : W2;
    _Float16* hiT = (z == 0) ? h0 : (z == 1) ? h1 : h2;
    _Float16* loT = (z == 0) ? l0 : (z == 1) ? l1 : nullptr;

    __shared__ float t[32][33];
    const int n0 = blockIdx.x * 32, k0 = blockIdx.y * 32;
    const int tx = threadIdx.x, ty = threadIdx.y;  // block (32,8)
    #pragma unroll
    for (int i = 0; i < 4; ++i)
        t[ty + 8 * i][tx] = 256.f * W[(size_t)(k0 + ty + 8 * i) * dim + n0 + tx];
    __syncthreads();
    #pragma unroll
    for (int i = 0; i < 4; ++i) {
        const int nn = ty + 8 * i;
        const float v = t[tx][nn];  // 256*W[k0+tx][n0+nn]
        const _Float16 h = (_Float16)v;
        const size_t o = (size_t)(n0 + nn) * dim + k0 + tx;
        hiT[o] = h;
        if (loT) loT[o] = (_Float16)(v - (float)h);
    }
}

// One block per row: single pass. rowmax from pmax partials (64/row);
// P = exp(s - rowmax) fp16 (unnormalized), rowsum fp32.
__global__ __launch_bounds__(256) void softmax_p(
    const float* __restrict__ Sc, const float* __restrict__ pmax,
    _Float16* __restrict__ P, float* __restrict__ rowsum)
{
    __shared__ float red[8];
    const int tid = threadIdx.x;
    const int row = blockIdx.x;
    const float* srow = Sc + (size_t)row * 4096;
    _Float16* prow = P + (size_t)row * 4096;

    if (tid < 64) {
        float m = pmax[(size_t)row * 64 + tid];
        #pragma unroll
        for (int off = 32; off; off >>= 1) m = fmaxf(m, __shfl_xor(m, off));
        if (tid == 0) red[0] = m;
    }
    __syncthreads();
    const float rmax = red[0];

    float s = 0.f;
    for (int c = tid * 4; c < 4096; c += 1024) {
        float4 v = *(const float4*)(srow + c);
        float p0 = __expf(v.x - rmax), p1 = __expf(v.y - rmax);
        float p2 = __expf(v.z - rmax), p3 = __expf(v.w - rmax);
        s += p0 + p1 + p2 + p3;
        half4v h = {(_Float16)p0, (_Float16)p1, (_Float16)p2, (_Float16)p3};
        *(half4v*)(prow + c) = h;
    }
    #pragma unroll
    for (int off = 32; off; off >>= 1) s += __shfl_xor(s, off, 64);
    if ((tid & 63) == 0) red[4 + (tid >> 6)] = s;
    __syncthreads();
    if (tid == 0) rowsum[row] = red[4] + red[5] + red[6] + red[7];
}

extern "C" void kernel_launch(void* const* d_in, const int* in_sizes, int n_in,
                              void* d_out, int out_size, void* d_ws, size_t ws_size,
                              hipStream_t stream) {
    const int Bb = 4, S = 4096, D = 1024;
    const size_t SD = (size_t)S * D;      // 4.19M
    const size_t SS = (size_t)S * S;      // 16.8M

    const float* x  = (const float*)d_in[0];
    const float* WQ = (const float*)d_in[1];
    const float* WK = (const float*)d_in[2];
    const float* WV = (const float*)d_in[3];
    float* out = (float*)d_out;

    // Workspace layout (~164 MB; ws_size in [209.7, 218) MB per R0 probe).
    char* w = (char*)d_ws;
    _Float16* WQhT = (_Float16*)w;  w += (size_t)D * D * 2;
    _Float16* WQlT = (_Float16*)w;  w += (size_t)D * D * 2;
    _Float16* WKhT = (_Float16*)w;  w += (size_t)D * D * 2;
    _Float16* WKlT = (_Float16*)w;  w += (size_t)D * D * 2;
    _Float16* WvhT = (_Float16*)w;  w += (size_t)D * D * 2;
    _Float16* xhi  = (_Float16*)w;  w += SD * 2;
    _Float16* xlo  = (_Float16*)w;  w += SD * 2;
    _Float16* Qhi  = (_Float16*)w;  w += SD * 2;
    _Float16* Qlo  = (_Float16*)w;  w += SD * 2;
    _Float16* Khi  = (_Float16*)w;  w += SD * 2;
    _Float16* Klo  = (_Float16*)w;  w += SD * 2;
    _Float16* VT   = (_Float16*)w;  w += SD * 2;
    float*    rowsum = (float*)w;   w += (size_t)S * 4;
    float*    pmax = (float*)w;     w += (size_t)S * 64 * 4;
    float*    Sc   = (float*)w;     w += SS * 4;
    _Float16* P    = (_Float16*)w;  w += SS * 2;

    const float kInv256 = 0.00390625f;           // 2^-8
    const float kScScale = 4.76837158203125e-7f; // 2^-21 = 1/(65536*32)

    dim3 blk(256);

    // Weight prep: 256*W^T split fp16 (Wv: hi only), one z=3 launch.
    wprep3<<<dim3(32, 32, 3), dim3(32, 8), 0, stream>>>(
        WQ, WK, WV, WQhT, WQlT, WKhT, WKlT, WvhT, D);

    for (int b = 0; b < Bb; ++b) {
        const float* xb = x + (size_t)b * SD;
        float* outb = out + (size_t)b * SD;

        split_scale<<<dim3(4096), blk, 0, stream>>>(xb, xhi, xlo, (int)SD);

        // Q and K projections (z-fused): [4096x1024] = split(x') @ split(W'^T)
        gemm_nt<true, 3, false><<<dim3(D / 128, S / 128, 2), blk, 0, stream>>>(
            xhi, xlo, WQhT, WQlT, Qhi, Qlo, nullptr, nullptr, kInv256, S, D, D,
            WKhT, WKlT, Khi, Klo);

        // VT'' = 256*V^T: [1024x4096] = WvhT' @ xhi'^T
        gemm_nt<false, 2, false><<<dim3(S / 128, D / 128, 1), blk, 0, stream>>>(
            WvhT, nullptr, xhi, nullptr, VT, nullptr, nullptr, nullptr, kInv256,
            D, S, D, nullptr, nullptr, nullptr, nullptr);

        // Sc = QK^T/32 fp32 + partial rowmax: [4096x4096]
        gemm_nt<true, 0, true><<<dim3(S / 128, S / 128, 1), blk, 0, stream>>>(
            Qhi, Qlo, Khi, Klo, Sc, nullptr, nullptr, pmax, kScScale, S, S, D,
            nullptr, nullptr, nullptr, nullptr);

        softmax_p<<<dim3(S), blk, 0, stream>>>(Sc, pmax, P, rowsum);

        // Z = (P @ V) / rowsum: [4096x1024], acc = 256*PV -> *2^-8/rowsum
        gemm_nt<false, 1, false><<<dim3(D / 128, S / 128, 1), blk, 0, stream>>>(
            P, nullptr, VT, nullptr, outb, nullptr, rowsum, nullptr, kInv256,
            S, D, S, nullptr, nullptr, nullptr, nullptr);
    }
}